// Round 1
// baseline (250.687 us; speedup 1.0000x reference)
//
#include <hip/hip_runtime.h>
#include <math.h>

#define B 2
#define S 1024
#define H 8
#define DIM 128
#define NCMP 63      // (1024-32)/16+1
#define NSLC 61      // (1024-64)/16+1
#define LCMP 32
#define QB 64        // BLOCK_Q
#define NQB (S/QB)   // 16
#define WIN 128
#define SCALE 0.08838834764831845f   // 128^-0.5

// ---------------- kernel 1: compressed K/V ----------------
__global__ __launch_bounds__(128) void cmp_kv_kernel(
    const float* __restrict__ k, const float* __restrict__ v,
    const float* __restrict__ wck, const float* __restrict__ bck,
    const float* __restrict__ wcv, const float* __restrict__ bcv,
    float* __restrict__ Kc, float* __restrict__ Vc)
{
  int d = threadIdx.x;
  int n = blockIdx.x;      // 0..62
  int h = blockIdx.y;
  int b = blockIdx.z;
  int s0 = n * 16;
  float sk = 0.f, sv = 0.f;
  #pragma unroll
  for (int l = 0; l < LCMP; ++l) {
    size_t gi = (((size_t)b*S + s0 + l)*H + h)*(size_t)DIM + d;
    sk += wck[l] * k[gi];
    sv += wcv[l] * v[gi];
  }
  size_t oi = (((size_t)(b*H + h)*NCMP + n)*(size_t)DIM) + d;
  Kc[oi] = sk + bck[0];
  Vc[oi] = sv + bcv[0];
}

// ---------------- wave reductions (wave64) ----------------
__device__ __forceinline__ float wave_max(float x) {
  #pragma unroll
  for (int off = 32; off > 0; off >>= 1) x = fmaxf(x, __shfl_xor(x, off));
  return x;
}
__device__ __forceinline__ float wave_sum(float x) {
  #pragma unroll
  for (int off = 32; off > 0; off >>= 1) x += __shfl_xor(x, off);
  return x;
}

// ---------------- staging helpers ----------------
// k-tile transposed into kT[d][j]; invalid rows zero-filled.
__device__ __forceinline__ void stage_kT_global(const float* __restrict__ kg, int b, int h,
                                                int row0, int tid, float (*kTl)[65]) {
  #pragma unroll
  for (int r = 0; r < 8; ++r) {
    int idx = (r << 10) + tid;        // 8192 = 64 rows * 128 d
    int j = idx >> 7, d = idx & 127;
    int row = row0 + j;
    float val = 0.f;
    if (row >= 0 && row < S) val = kg[(((size_t)b*S + row)*H + h)*(size_t)DIM + d];
    kTl[d][j] = val;
  }
}
__device__ __forceinline__ void stage_v_global(const float* __restrict__ vg, int b, int h,
                                               int row0, int tid, float (*vl)[DIM]) {
  #pragma unroll
  for (int r = 0; r < 8; ++r) {
    int idx = (r << 10) + tid;
    int j = idx >> 7, d = idx & 127;
    int row = row0 + j;
    float val = 0.f;
    if (row >= 0 && row < S) val = vg[(((size_t)b*S + row)*H + h)*(size_t)DIM + d];
    vl[j][d] = val;
  }
}

// QK: lane owns key (column of kT), 4 queries per wave, q broadcast from LDS.
__device__ __forceinline__ void qk_tile(const float (*qld)[DIM], const float (*kTl)[65],
                                        int q0, int lane, float sc[4]) {
  float a0 = 0.f, a1 = 0.f, a2 = 0.f, a3 = 0.f;
  #pragma unroll 8
  for (int d4 = 0; d4 < DIM; d4 += 4) {
    float4 qa = *(const float4*)&qld[q0+0][d4];
    float4 qb = *(const float4*)&qld[q0+1][d4];
    float4 qc = *(const float4*)&qld[q0+2][d4];
    float4 qd = *(const float4*)&qld[q0+3][d4];
    float k0 = kTl[d4+0][lane];
    float k1 = kTl[d4+1][lane];
    float k2 = kTl[d4+2][lane];
    float k3 = kTl[d4+3][lane];
    a0 += qa.x*k0 + qa.y*k1 + qa.z*k2 + qa.w*k3;
    a1 += qb.x*k0 + qb.y*k1 + qb.z*k2 + qb.w*k3;
    a2 += qc.x*k0 + qc.y*k1 + qc.z*k2 + qc.w*k3;
    a3 += qd.x*k0 + qd.y*k1 + qd.z*k2 + qd.w*k3;
  }
  sc[0]=a0; sc[1]=a1; sc[2]=a2; sc[3]=a3;
}

// ---------------- kernel 2: mega (one block per b,h,q-block) ----------------
__global__ __launch_bounds__(1024) void nsa_mega(
    const float* __restrict__ qg, const float* __restrict__ kg, const float* __restrict__ vg,
    const float* __restrict__ Kc, const float* __restrict__ Vc,
    const float* __restrict__ wgate, const float* __restrict__ bgate,
    float* __restrict__ outg)
{
  __shared__ float q_lds[QB][DIM];     // 32 KB
  __shared__ float kT[DIM][65];        // 33.3 KB  (transposed keys, padded)
  __shared__ float v_lds[64][DIM];     // 32 KB
  __shared__ float p_lds[QB][128];     // 32 KB
  __shared__ float S_col[64];
  __shared__ float gw[3][DIM];
  __shared__ int   sel[2];

  const int tid  = threadIdx.x;
  const int lane = tid & 63;
  const int wid  = tid >> 6;           // 0..15
  const int qb   = blockIdx.x;
  const int h    = blockIdx.y;
  const int b    = blockIdx.z;
  const int bh   = b*H + h;
  const int q0   = wid * 4;            // local query base (4 queries / wave)
  const int iq0  = qb*QB + q0;         // global query base

  // ---- stage q tile + gate weights ----
  #pragma unroll
  for (int r = 0; r < 8; ++r) {
    int idx = (r << 10) + tid;
    int qq = idx >> 7, d = idx & 127;
    q_lds[qq][d] = qg[(((size_t)b*S + qb*QB + qq)*H + h)*(size_t)DIM + d];
  }
  if (tid < 384) gw[tid >> 7][tid & 127] = wgate[tid];

  // ---- stage compressed K^T / V ----
  const float* KcBH = Kc + (size_t)bh*NCMP*DIM;
  const float* VcBH = Vc + (size_t)bh*NCMP*DIM;
  #pragma unroll
  for (int r = 0; r < 8; ++r) {
    int idx = (r << 10) + tid;
    if (idx < NCMP*DIM) {
      int j = idx >> 7, d = idx & 127;
      kT[d][j]    = KcBH[idx];
      v_lds[j][d] = VcBH[idx];
    }
  }
  if (tid < DIM) { kT[tid][63] = 0.f; v_lds[63][tid] = 0.f; }
  __syncthreads();

  // ---- compressed branch: QK + softmax ----
  float accC0[4] = {0,0,0,0}, accC1[4] = {0,0,0,0};
  {
    float sc[4];
    qk_tile(q_lds, kT, q0, lane, sc);
    #pragma unroll
    for (int qq = 0; qq < 4; ++qq) {
      float sv = (lane < NCMP) ? (sc[qq] / SCALE) : -INFINITY;   // reference divides by scale!
      float m = wave_max(sv);
      float p = expf(sv - m);           // masked lanes -> 0
      float l = wave_sum(p);
      p_lds[q0+qq][lane] = p / l;       // normalized P_cmp
    }
  }
  __syncthreads();

  // ---- compressed PV ----
  {
    int d0 = lane * 2;
    #pragma unroll 4
    for (int j = 0; j < 64; ++j) {
      float2 vv = *(const float2*)&v_lds[j][d0];
      #pragma unroll
      for (int qq = 0; qq < 4; ++qq) {
        float pj = p_lds[q0+qq][j];
        accC0[qq] += pj * vv.x;
        accC1[qq] += pj * vv.y;
      }
    }
  }

  // ---- selection scoring: group-sum P_cmp -> M-map -> top-2 (wave 0) ----
  if (wid == 0) {
    float ssum = 0.f;
    if (lane < NCMP) {
      for (int qq2 = 0; qq2 < QB; ++qq2) ssum += p_lds[qq2][lane];
    }
    S_col[lane] = ssum;
    asm volatile("s_waitcnt lgkmcnt(0)" ::: "memory");
    float val = -INFINITY;
    if (lane < NSLC) {
      const float wts[5] = {1.f, 2.f, 2.f, 2.f, 1.f};
      float a = 0.f;
      #pragma unroll
      for (int o = 0; o < 5; ++o) {
        int i = 4*lane - o;
        if (i >= 0 && i < NCMP) a += wts[o] * S_col[i];
      }
      val = a;
    }
    // argmax (tie -> smaller index), twice
    float v1 = val; int i1 = lane;
    #pragma unroll
    for (int off = 32; off > 0; off >>= 1) {
      float ov = __shfl_xor(v1, off); int oi = __shfl_xor(i1, off);
      if (ov > v1 || (ov == v1 && oi < i1)) { v1 = ov; i1 = oi; }
    }
    int s0i = i1;
    float v2 = (lane == s0i) ? -INFINITY : val; int i2 = lane;
    #pragma unroll
    for (int off = 32; off > 0; off >>= 1) {
      float ov = __shfl_xor(v2, off); int oi = __shfl_xor(i2, off);
      if (ov > v2 || (ov == v2 && oi < i2)) { v2 = ov; i2 = oi; }
    }
    if (lane == 0) { sel[0] = s0i; sel[1] = i2; }
  }
  __syncthreads();

  // ---- selected branch: 2 blocks of 64 keys ----
  float accS0[4] = {0,0,0,0}, accS1[4] = {0,0,0,0};
  {
    int rowA = sel[0] * 16;
    int rowB = sel[1] * 16;
    float scA[4], scB[4];

    stage_kT_global(kg, b, h, rowA, tid, kT);
    __syncthreads();
    qk_tile(q_lds, kT, q0, lane, scA);
    __syncthreads();
    stage_kT_global(kg, b, h, rowB, tid, kT);
    __syncthreads();
    qk_tile(q_lds, kT, q0, lane, scB);

    #pragma unroll
    for (int qq = 0; qq < 4; ++qq) {
      float aA = scA[qq] * SCALE;
      float aB = scB[qq] * SCALE;
      float m = wave_max(fmaxf(aA, aB));
      float pA = expf(aA - m);
      float pB = expf(aB - m);
      float l = wave_sum(pA + pB);
      p_lds[q0+qq][lane]      = pA / l;
      p_lds[q0+qq][64 + lane] = pB / l;
    }
    __syncthreads();

    stage_v_global(vg, b, h, rowA, tid, v_lds);
    __syncthreads();
    {
      int d0 = lane * 2;
      #pragma unroll 4
      for (int j = 0; j < 64; ++j) {
        float2 vv = *(const float2*)&v_lds[j][d0];
        #pragma unroll
        for (int qq = 0; qq < 4; ++qq) {
          float pj = p_lds[q0+qq][j];
          accS0[qq] += pj * vv.x;
          accS1[qq] += pj * vv.y;
        }
      }
    }
    __syncthreads();
    stage_v_global(vg, b, h, rowB, tid, v_lds);
    __syncthreads();
    {
      int d0 = lane * 2;
      #pragma unroll 4
      for (int j = 0; j < 64; ++j) {
        float2 vv = *(const float2*)&v_lds[j][d0];
        #pragma unroll
        for (int qq = 0; qq < 4; ++qq) {
          float pj = p_lds[q0+qq][64 + j];
          accS0[qq] += pj * vv.x;
          accS1[qq] += pj * vv.y;
        }
      }
    }
  }

  // ---- window branch: online softmax over 6 tiles ----
  float accW0[4] = {0,0,0,0}, accW1[4] = {0,0,0,0};
  float mW[4] = {-INFINITY,-INFINITY,-INFINITY,-INFINITY};
  float lW[4] = {0,0,0,0};

  for (int t = 0; t < 6; ++t) {
    __syncthreads();                       // previous tile fully consumed
    int jt = qb*QB - WIN + t*64;
    stage_kT_global(kg, b, h, jt, tid, kT);
    stage_v_global(vg, b, h, jt, tid, v_lds);
    __syncthreads();

    float sc[4];
    qk_tile(q_lds, kT, q0, lane, sc);
    int jabs = jt + lane;
    bool gv = (jabs >= 0) && (jabs < S);
    float alpha[4];
    #pragma unroll
    for (int qq = 0; qq < 4; ++qq) {
      int ig = iq0 + qq;
      bool valid = gv && (jabs >= ig - WIN) && (jabs <= ig + WIN);
      float sv = valid ? (sc[qq] * SCALE) : -INFINITY;
      float tmax = wave_max(sv);
      float mnew = fmaxf(mW[qq], tmax);
      float pj;
      if (mnew == -INFINITY) {             // fully-masked tile for this query
        pj = 0.f; alpha[qq] = 1.f;
      } else {
        alpha[qq] = expf(mW[qq] - mnew);   // mW=-inf -> 0
        pj = expf(sv - mnew);              // sv=-inf -> 0
        lW[qq] = lW[qq] * alpha[qq] + wave_sum(pj);
        mW[qq] = mnew;
      }
      p_lds[q0+qq][lane] = pj;
    }
    __syncthreads();

    int d0 = lane * 2;
    #pragma unroll
    for (int qq = 0; qq < 4; ++qq) { accW0[qq] *= alpha[qq]; accW1[qq] *= alpha[qq]; }
    #pragma unroll 4
    for (int j = 0; j < 64; ++j) {
      float2 vv = *(const float2*)&v_lds[j][d0];
      #pragma unroll
      for (int qq = 0; qq < 4; ++qq) {
        float pj = p_lds[q0+qq][j];
        accW0[qq] += pj * vv.x;
        accW1[qq] += pj * vv.y;
      }
    }
  }
  #pragma unroll
  for (int qq = 0; qq < 4; ++qq) { accW0[qq] /= lW[qq]; accW1[qq] /= lW[qq]; }

  // ---- gate + combine + write ----
  {
    int d0 = lane * 2;
    #pragma unroll
    for (int qq = 0; qq < 4; ++qq) {
      int qi = q0 + qq;
      float g[3];
      #pragma unroll
      for (int c = 0; c < 3; ++c) {
        float part = q_lds[qi][d0] * gw[c][d0] + q_lds[qi][d0+1] * gw[c][d0+1];
        part = wave_sum(part);
        g[c] = 1.f / (1.f + expf(-(part + bgate[c])));
      }
      float o0 = g[0]*accC0[qq] + g[1]*accS0[qq] + g[2]*accW0[qq];
      float o1 = g[0]*accC1[qq] + g[1]*accS1[qq] + g[2]*accW1[qq];
      size_t oi = (((size_t)b*S + iq0 + qq)*H + h)*(size_t)DIM + d0;
      *(float2*)&outg[oi] = make_float2(o0, o1);
    }
  }
}

extern "C" void kernel_launch(void* const* d_in, const int* in_sizes, int n_in,
                              void* d_out, int out_size, void* d_ws, size_t ws_size,
                              hipStream_t stream) {
  const float* q   = (const float*)d_in[0];
  const float* k   = (const float*)d_in[1];
  const float* v   = (const float*)d_in[2];
  const float* wck = (const float*)d_in[3];
  const float* bck = (const float*)d_in[4];
  const float* wcv = (const float*)d_in[5];
  const float* bcv = (const float*)d_in[6];
  const float* wg  = (const float*)d_in[7];
  const float* bg  = (const float*)d_in[8];
  float* out = (float*)d_out;

  float* Kc = (float*)d_ws;
  float* Vc = Kc + (size_t)B*H*NCMP*DIM;

  cmp_kv_kernel<<<dim3(NCMP, H, B), 128, 0, stream>>>(k, v, wck, bck, wcv, bcv, Kc, Vc);
  nsa_mega<<<dim3(NQB, H, B), 1024, 0, stream>>>(q, k, v, Kc, Vc, wg, bg, out);
}